// Round 4
// baseline (525.434 us; speedup 1.0000x reference)
//
#include <hip/hip_runtime.h>

#define NC 21
#define NB 8
#define HW (512*512)
#define EPS 1e-8f
#define CM_N (NC * NC)   // 441
#define PLANE4 (HW / 4)  // 65536 float4 per channel plane

// ---------------------------------------------------------------------------
// K1: pure argmax streamer. Reads input (176 MB), writes u8 pred (2 MB).
// No LDS, no atomics — isolates the 21-plane strided-load pattern.
// Two independent compare chains (even/odd c) for MLP.
__global__ __launch_bounds__(256) void k_argmax(const float* __restrict__ input,
                                                uchar4* __restrict__ pred4) {
    const int g = blockIdx.x * 256 + threadIdx.x;   // float4-task id, NB*PLANE4 total
    const int b = g >> 16;                          // g / PLANE4
    const int q = g & 65535;                        // g % PLANE4
    const float4* ip = (const float4*)(input + (size_t)b * NC * HW);

    float4 m0 = ip[q];                // chain 0: c = 0,2,4,...,20
    float4 m1 = ip[PLANE4 + q];       // chain 1: c = 1,3,...,19
    int j0x = 0, j0y = 0, j0z = 0, j0w = 0;
    int j1x = 1, j1y = 1, j1z = 1, j1w = 1;
    #pragma unroll
    for (int c = 2; c < NC; c += 2) {
        float4 v0 = ip[c * PLANE4 + q];
        float4 v1 = (c + 1 < NC) ? ip[(c + 1) * PLANE4 + q] : make_float4(0, 0, 0, 0);
        if (v0.x > m0.x) { m0.x = v0.x; j0x = c; }
        if (v0.y > m0.y) { m0.y = v0.y; j0y = c; }
        if (v0.z > m0.z) { m0.z = v0.z; j0z = c; }
        if (v0.w > m0.w) { m0.w = v0.w; j0w = c; }
        if (c + 1 < NC) {
            if (v1.x > m1.x) { m1.x = v1.x; j1x = c + 1; }
            if (v1.y > m1.y) { m1.y = v1.y; j1y = c + 1; }
            if (v1.z > m1.z) { m1.z = v1.z; j1z = c + 1; }
            if (v1.w > m1.w) { m1.w = v1.w; j1w = c + 1; }
        }
    }
    // merge, exact first-max tie-break (== -> smaller index)
    int jx = (m1.x > m0.x || (m1.x == m0.x && j1x < j0x)) ? j1x : j0x;
    int jy = (m1.y > m0.y || (m1.y == m0.y && j1y < j0y)) ? j1y : j0y;
    int jz = (m1.z > m0.z || (m1.z == m0.z && j1z < j0z)) ? j1z : j0z;
    int jw = (m1.w > m0.w || (m1.w == m0.w && j1w < j0w)) ? j1w : j0w;
    pred4[g] = make_uchar4((unsigned char)jx, (unsigned char)jy,
                           (unsigned char)jz, (unsigned char)jw);
}

// ---------------------------------------------------------------------------
// K2: scatter. Reads target (176 MB) + pred (2 MB); per-WAVE private LDS
// tables (4x contention reduction vs round 3), non-atomic partial flush.
// 512 blocks: each handles 4096 px (4 iters x 256 threads x float4).
__global__ __launch_bounds__(256) void k_scatter(const float* __restrict__ target,
                                                 const uchar4* __restrict__ pred4,
                                                 float* __restrict__ partial) {
    __shared__ float tbl[4 * CM_N];
    const int t = threadIdx.x;
    for (int i = t; i < 4 * CM_N; i += 256) tbl[i] = 0.0f;
    __syncthreads();
    float* wt = tbl + (t >> 6) * CM_N;              // this wave's private table

    const int b  = blockIdx.x >> 6;                 // 64 blocks per batch
    const int q0 = (blockIdx.x & 63) * 1024;
    const float4* tp = (const float4*)(target + (size_t)b * NC * HW);
    const uchar4* pp = pred4 + (size_t)b * PLANE4;

    for (int it = 0; it < 4; ++it) {
        const int q = q0 + it * 256 + t;
        const uchar4 pj = pp[q];
        #pragma unroll
        for (int i = 0; i < NC; ++i) {
            float4 y = tp[i * PLANE4 + q];
            const int row = i * NC;
            atomicAdd(&wt[row + pj.x], y.x);
            atomicAdd(&wt[row + pj.y], y.y);
            atomicAdd(&wt[row + pj.z], y.z);
            atomicAdd(&wt[row + pj.w], y.w);
        }
    }
    __syncthreads();

    float* dst = partial + (size_t)blockIdx.x * CM_N;
    for (int i = t; i < CM_N; i += 256)
        dst[i] = tbl[i] + tbl[CM_N + i] + tbl[2 * CM_N + i] + tbl[3 * CM_N + i];
}

// ---------------------------------------------------------------------------
// K3: tree-reduce 512 partial slots -> per-batch cm. 64 blocks of 64 slots/8.
__global__ __launch_bounds__(256) void cm_reduce(const float* __restrict__ partial,
                                                 float* __restrict__ cm) {
    const int b = blockIdx.x >> 3;                  // 8 segs per batch
    const int s = blockIdx.x & 7;
    const float* base = partial + ((size_t)b * 64 + (size_t)s * 8) * CM_N;
    const int t = threadIdx.x;
    float a0 = 0.0f, a1 = 0.0f;
    for (int k = 0; k < 8; ++k) {
        const float* p = base + (size_t)k * CM_N;
        a0 += p[t];
        if (t < CM_N - 256) a1 += p[256 + t];
    }
    atomicAdd(&cm[b * CM_N + t], a0);
    if (t < CM_N - 256) atomicAdd(&cm[b * CM_N + 256 + t], a1);
}

// ---------------------------------------------------------------------------
// K4: rowsum (exact: one-hot sums to 1 per pixel), normalize, mean over batch.
__global__ __launch_bounds__(512) void cm_final(const float* __restrict__ cm,
                                                float* __restrict__ out) {
    __shared__ float rs[NB * NC];
    const int t = threadIdx.x;
    if (t < NB * NC) {
        const int b = t / NC, i = t % NC;
        float s = 0.0f;
        for (int j = 0; j < NC; ++j) s += cm[b * CM_N + i * NC + j];
        rs[t] = s + EPS;
    }
    __syncthreads();
    if (t < CM_N) {
        const int i = t / NC;
        float acc = 0.0f;
        for (int b = 0; b < NB; ++b) acc += cm[b * CM_N + t] / rs[b * NC + i];
        out[t] = acc * (1.0f / NB);
    }
}

extern "C" void kernel_launch(void* const* d_in, const int* in_sizes, int n_in,
                              void* d_out, int out_size, void* d_ws, size_t ws_size,
                              hipStream_t stream) {
    const float* input  = (const float*)d_in[0];
    const float* target = (const float*)d_in[1];
    float* out = (float*)d_out;

    // ws: cm[8*441] | partial[512*441] | pred[2 MB u8]   (total 3.01 MB)
    float*  cm      = (float*)d_ws;
    float*  partial = cm + NB * CM_N;
    uchar4* pred4   = (uchar4*)(partial + 512 * CM_N);

    hipMemsetAsync(cm, 0, NB * CM_N * sizeof(float), stream);
    k_argmax <<<NB * 256, 256, 0, stream>>>(input, pred4);
    k_scatter<<<512,      256, 0, stream>>>(target, pred4, partial);
    cm_reduce<<<64,       256, 0, stream>>>(partial, cm);
    cm_final <<<1,        512, 0, stream>>>(cm, out);
}